// Round 15
// baseline (1022.355 us; speedup 1.0000x reference)
//
#include <hip/hip_runtime.h>
#include <math.h>

#define C 128
#define K 16
#define GP 8             // points per group
#define GROWS 128        // GP*K rows per group tile

typedef unsigned short ushort_t;
typedef unsigned int u32;
typedef float f32x4 __attribute__((ext_vector_type(4)));
typedef float f32x16 __attribute__((ext_vector_type(16)));
typedef _Float16 f16x8 __attribute__((ext_vector_type(8)));

union U8h { _Float16 h[8]; uint4 u; };

__device__ __forceinline__ float f16tof(ushort_t b) {
    _Float16 h = __builtin_bit_cast(_Float16, b); return (float)h;
}
__device__ __forceinline__ ushort_t ftof16(float f) {
    _Float16 h = (_Float16)f; return __builtin_bit_cast(ushort_t, h);
}
__device__ __forceinline__ f32x4 mfma16(f16x8 a, f16x8 b, f32x4 c) {
    return __builtin_amdgcn_mfma_f32_16x16x32_f16(a, b, c, 0, 0, 0);
}
__device__ __forceinline__ f32x16 mfma32(f16x8 a, f16x8 b, f32x16 c) {
    return __builtin_amdgcn_mfma_f32_32x32x16_f16(a, b, c, 0, 0, 0);
}

// select neighbor index for C-frag reg r (all constants under full unroll)
#define GETJ(r) ((r) < 4 ? ((r)==0?ja0.x:(r)==1?ja0.y:(r)==2?ja0.z:ja0.w)      \
               : (r) < 8 ? ((r)==4?jb0.x:(r)==5?jb0.y:(r)==6?jb0.z:jb0.w)      \
               : (r) <12 ? ((r)==8?ja1.x:(r)==9?ja1.y:(r)==10?ja1.z:ja1.w)     \
                         : ((r)==12?jb1.x:(r)==13?jb1.y:(r)==14?jb1.z:jb1.w))

// ---------------------------------------------------------------------------
// Prep: transpose+convert 4 weight matrices fp32 -> fp16, WT[n][e] layout.
// ---------------------------------------------------------------------------
__global__ __launch_bounds__(128) void k_prep(
    const float* __restrict__ s0, const float* __restrict__ s1,
    const float* __restrict__ s2, const float* __restrict__ s3,
    ushort_t* __restrict__ d0, ushort_t* __restrict__ d1,
    ushort_t* __restrict__ d2, ushort_t* __restrict__ d3)
{
    const int m = blockIdx.x >> 7, n = blockIdx.x & 127, e = threadIdx.x;
    const float* s = (m==0) ? s0 : (m==1) ? s1 : (m==2) ? s2 : s3;
    ushort_t*   d = (m==0) ? d0 : (m==1) ? d1 : (m==2) ? d2 : d3;
    d[n*C + e] = ftof16(s[e*C + n]);
}

// ---------------------------------------------------------------------------
// Kernel 1: h = x@W_top + b; phi/psi/alpha = h@W_* + b   via f16 MFMA.
// ---------------------------------------------------------------------------
__global__ __launch_bounds__(512) void k_qkv2(
    const float* __restrict__ x,
    const ushort_t* __restrict__ WTt, const float* __restrict__ bt,
    const ushort_t* __restrict__ WTp, const float* __restrict__ bp,
    const ushort_t* __restrict__ WTs, const float* __restrict__ bs,
    const ushort_t* __restrict__ WTa, const float* __restrict__ ba,
    ushort_t* __restrict__ phiB, ushort_t* __restrict__ psiB,
    ushort_t* __restrict__ alfB)
{
    __shared__ ushort_t sX[64*C];
    __shared__ ushort_t sH[64*C];
    const int tid = threadIdx.x, lane = tid & 63, wv = tid >> 6;
    const int ncol = (wv<<4) + (lane&15), arow = lane&15;
    const int kgrp = lane>>4, krow0 = kgrp<<3;
    const int r0 = blockIdx.x * 64;

    {
        const int rX = tid>>3, cX = (tid&7)<<4;
        const float* xp = &x[(size_t)(r0+rX)*C + cX];
        #pragma unroll
        for (int hf = 0; hf < 2; ++hf) {
            const float4 a  = *(const float4*)&xp[hf*8 + 0];
            const float4 b2 = *(const float4*)&xp[hf*8 + 4];
            U8h v;
            v.h[0]=(_Float16)a.x;  v.h[1]=(_Float16)a.y;
            v.h[2]=(_Float16)a.z;  v.h[3]=(_Float16)a.w;
            v.h[4]=(_Float16)b2.x; v.h[5]=(_Float16)b2.y;
            v.h[6]=(_Float16)b2.z; v.h[7]=(_Float16)b2.w;
            const int col = cX + hf*8;
            *(uint4*)&sX[(rX<<7) + (col ^ ((rX&7)<<3))] = v.u;
        }
    }
    __syncthreads();

    {
        f16x8 bf[4]; f32x4 hacc[4];
        #pragma unroll
        for (int kk = 0; kk < 4; ++kk)
            bf[kk] = *(const f16x8*)&WTt[(size_t)ncol*C + (kk<<5) + krow0];
        #pragma unroll
        for (int m = 0; m < 4; ++m) hacc[m] = (f32x4){0.f,0.f,0.f,0.f};
        __builtin_amdgcn_s_setprio(1);
        #pragma unroll
        for (int m = 0; m < 4; ++m)
            #pragma unroll
            for (int kk = 0; kk < 4; ++kk) {
                const int row = (m<<4) + arow;
                const f16x8 af = *(const f16x8*)&sX[(row<<7) + (((kk<<5)+krow0) ^ ((row&7)<<3))];
                hacc[m] = mfma16(af, bf[kk], hacc[m]);
            }
        __builtin_amdgcn_s_setprio(0);
        const float btc = bt[ncol];
        #pragma unroll
        for (int m = 0; m < 4; ++m)
            #pragma unroll
            for (int r = 0; r < 4; ++r) {
                const int row = (m<<4) + (kgrp<<2) + r;
                sH[(row<<7) + (ncol ^ ((row&7)<<3))] = ftof16(hacc[m][r] + btc);
            }
    }
    __syncthreads();

#define OGEMM(WT_, b_, o_)                                                    \
    {                                                                         \
        f16x8 wf[4]; f32x4 oacc[4];                                           \
        _Pragma("unroll")                                                     \
        for (int kk = 0; kk < 4; ++kk)                                        \
            wf[kk] = *(const f16x8*)&WT_[(size_t)ncol*C + (kk<<5) + krow0];   \
        _Pragma("unroll")                                                     \
        for (int m = 0; m < 4; ++m) oacc[m] = (f32x4){0.f,0.f,0.f,0.f};      \
        __builtin_amdgcn_s_setprio(1);                                        \
        _Pragma("unroll")                                                     \
        for (int m = 0; m < 4; ++m)                                           \
            _Pragma("unroll")                                                 \
            for (int kk = 0; kk < 4; ++kk) {                                  \
                const int row = (m<<4) + arow;                                \
                const f16x8 af = *(const f16x8*)&sH[(row<<7) + (((kk<<5)+krow0) ^ ((row&7)<<3))]; \
                oacc[m] = mfma16(af, wf[kk], oacc[m]);                        \
            }                                                                 \
        __builtin_amdgcn_s_setprio(0);                                        \
        const float bc = b_[ncol];                                            \
        _Pragma("unroll")                                                     \
        for (int m = 0; m < 4; ++m)                                           \
            _Pragma("unroll")                                                 \
            for (int r = 0; r < 4; ++r) {                                     \
                const int row = (m<<4) + (kgrp<<2) + r;                       \
                o_[(size_t)(r0+row)*C + ncol] = ftof16(oacc[m][r] + bc);      \
            }                                                                 \
    }
    OGEMM(WTp, bp, phiB)
    OGEMM(WTs, bs, psiB)
    OGEMM(WTa, ba, alfB)
#undef OGEMM
}

// ---------------------------------------------------------------------------
// Kernel 2: fused vector attention via 32x32x16 MFMA, 8 points per group.
// 512 thr / 8 waves: wave = (32-row chunk = 2 points) x (64-col half).
// A-frag read once per kk, shared across 2 col-tiles (read:MFMA = 1:2).
// pos kept in registers (f32x16 x2); gathers wave-coalesced and hoisted.
// (512,2): 256 unified regs/wave -> no spill. LDS = 66KB (T + A tiles).
// ---------------------------------------------------------------------------
__global__ __launch_bounds__(512, 2) void k_attn13(
    const ushort_t* __restrict__ phiB, const ushort_t* __restrict__ psiB,
    const ushort_t* __restrict__ alfB,
    const float* __restrict__ coords, const int* __restrict__ nidx,
    const float* __restrict__ Wd1, const float* __restrict__ bd1,
    const ushort_t* __restrict__ WTd2, const float* __restrict__ bd2,
    const ushort_t* __restrict__ WTg1, const float* __restrict__ bg1,
    const ushort_t* __restrict__ WTg2,
    ushort_t* __restrict__ yB,
    int ngroups, int gpb)
{
    __shared__ ushort_t sT[GROWS*C];   // t1, then u
    __shared__ ushort_t sA[GROWS*C];   // attn
    __shared__ float    sW1b[512];     // Wd1 (384) + bd1 (128)

    const int tid   = threadIdx.x, lane = tid & 63, wid = tid >> 6;
    const int chunk = wid >> 1;          // 0..3 : 32-row chunk
    const int ch0   = (wid & 1) << 6;    // 0 or 64 : col-half base
    const int lcol  = lane & 31;
    const int hi    = lane >> 5;
    const int col0  = ch0 + lcol;        // ct=0 column
    const int col1  = col0 + 32;         // ct=1 column
    const int arow  = (chunk << 5) + lcol;          // A-frag row
    const int asw   = (arow & 7) << 3;
    const int trow  = tid >> 2;          // phase-1 row 0..127
    const int tch   = (tid & 3) << 5;    // phase-1 ch base

    if (tid < 512) sW1b[tid] = (tid < 384) ? Wd1[tid] : bd1[tid - 384];

    const float bd2c0 = bd2[col0], bd2c1 = bd2[col1];
    const float bg1c0 = bg1[col0], bg1c1 = bg1[col1];

    const int g0 = blockIdx.x * gpb;
    if (g0 >= ngroups) return;
    const int gend = (g0 + gpb < ngroups) ? (g0 + gpb) : ngroups;

    __syncthreads();   // sW1b staged

    for (int g = g0; g < gend; ++g) {
        const int p0 = g * GP;

        // C-frag neighbor indices for this lane (rows of its 2 points)
        const int pt0 = p0 + (chunk<<1), pt1 = pt0 + 1;
        const int4 ja0 = *(const int4*)&nidx[(size_t)pt0*K + (hi<<2)];
        const int4 jb0 = *(const int4*)&nidx[(size_t)pt0*K + 8 + (hi<<2)];
        const int4 ja1 = *(const int4*)&nidx[(size_t)pt1*K + (hi<<2)];
        const int4 jb1 = *(const int4*)&nidx[(size_t)pt1*K + 8 + (hi<<2)];

        // hoisted gathers: psi (phase 2), phi, alpha (phase 4) — wave-coalesced
        ushort_t psv0[16], psv1[16], alv0[16], alv1[16];
        #pragma unroll
        for (int r = 0; r < 16; ++r) {
            const int j = GETJ(r);
            psv0[r] = psiB[(size_t)j*C + col0];
            psv1[r] = psiB[(size_t)j*C + col1];
            alv0[r] = alfB[(size_t)j*C + col0];
            alv1[r] = alfB[(size_t)j*C + col1];
        }
        const float ph00 = f16tof(phiB[(size_t)pt0*C + col0]);
        const float ph01 = f16tof(phiB[(size_t)pt0*C + col1]);
        const float ph10 = f16tof(phiB[(size_t)pt1*C + col0]);
        const float ph11 = f16tof(phiB[(size_t)pt1*C + col1]);

        // ======== phase 1: t1 = relu(rel@Wd1+bd1) -> sT ========
        {
            const int pt = p0 + (trow>>4);
            const int jt = nidx[(size_t)pt*K + (trow&15)];
            const float rx = coords[(size_t)pt*3+0] - coords[(size_t)jt*3+0];
            const float ry = coords[(size_t)pt*3+1] - coords[(size_t)jt*3+1];
            const float rz = coords[(size_t)pt*3+2] - coords[(size_t)jt*3+2];
            #pragma unroll
            for (int s = 0; s < 4; ++s) {
                U8h h;
                #pragma unroll
                for (int z = 0; z < 8; ++z) {
                    const int c = tch + (s<<3) + z;
                    float t = fmaf(rx, sW1b[c],
                              fmaf(ry, sW1b[128+c],
                              fmaf(rz, sW1b[256+c], sW1b[384+c])));
                    h.h[z] = (_Float16)fmaxf(t, 0.f);
                }
                *(uint4*)&sT[(trow<<7) + ((tch + (s<<3)) ^ ((trow&7)<<3))] = h.u;
            }
        }
        __syncthreads();                                        // S1

        // ======== phase 2: pos = t1@Wd2+b (regs); attn -> sA ========
        f32x16 pos0 = {0}, pos1 = {0};
        {
            __builtin_amdgcn_s_setprio(1);
            #pragma unroll
            for (int kk = 0; kk < 8; ++kk) {
                const int kc = (kk<<4) + (hi<<3);
                const f16x8 a  = *(const f16x8*)&sT[(arow<<7) + (kc ^ asw)];
                const f16x8 w0 = *(const f16x8*)&WTd2[(size_t)col0*C + kc];
                const f16x8 w1 = *(const f16x8*)&WTd2[(size_t)col1*C + kc];
                pos0 = mfma32(a, w0, pos0);
                pos1 = mfma32(a, w1, pos1);
            }
            __builtin_amdgcn_s_setprio(0);
            #pragma unroll
            for (int r = 0; r < 16; ++r) {
                const int lrow = (r&3) + (((r>>2)&1)<<3) + ((r>>3)<<4) + (hi<<2);
                const int grow = (chunk<<5) + lrow;
                const int sw   = (grow&7)<<3;
                const float pv0 = pos0[r] + bd2c0;
                const float pv1 = pos1[r] + bd2c1;
                pos0[r] = pv0; pos1[r] = pv1;
                const float ph_0 = (r < 8) ? ph00 : ph10;
                const float ph_1 = (r < 8) ? ph01 : ph11;
                const u32 v0 = ftof16(ph_0 - f16tof(psv0[r]) + pv0);
                const u32 v1 = ftof16(ph_1 - f16tof(psv1[r]) + pv1);
                const u32 p0v = (u32)__shfl_xor((int)v0, 1);
                const u32 p1v = (u32)__shfl_xor((int)v1, 1);
                if (!(lane&1)) {
                    *(u32*)&sA[(grow<<7) + ((col0&~1) ^ sw)] = v0 | (p0v<<16);
                    *(u32*)&sA[(grow<<7) + ((col1&~1) ^ sw)] = v1 | (p1v<<16);
                }
            }
        }
        __syncthreads();                                        // S2

        // ======== phase 3: u = relu(attn@Wg1+b) -> sT (overwrite) ========
        {
            f32x16 u0 = {0}, u1 = {0};
            __builtin_amdgcn_s_setprio(1);
            #pragma unroll
            for (int kk = 0; kk < 8; ++kk) {
                const int kc = (kk<<4) + (hi<<3);
                const f16x8 a  = *(const f16x8*)&sA[(arow<<7) + (kc ^ asw)];
                const f16x8 w0 = *(const f16x8*)&WTg1[(size_t)col0*C + kc];
                const f16x8 w1 = *(const f16x8*)&WTg1[(size_t)col1*C + kc];
                u0 = mfma32(a, w0, u0);
                u1 = mfma32(a, w1, u1);
            }
            __builtin_amdgcn_s_setprio(0);
            #pragma unroll
            for (int r = 0; r < 16; ++r) {
                const int lrow = (r&3) + (((r>>2)&1)<<3) + ((r>>3)<<4) + (hi<<2);
                const int grow = (chunk<<5) + lrow;
                const int sw   = (grow&7)<<3;
                const u32 v0 = ftof16(fmaxf(u0[r] + bg1c0, 0.f));
                const u32 v1 = ftof16(fmaxf(u1[r] + bg1c1, 0.f));
                const u32 p0v = (u32)__shfl_xor((int)v0, 1);
                const u32 p1v = (u32)__shfl_xor((int)v1, 1);
                if (!(lane&1)) {
                    *(u32*)&sT[(grow<<7) + ((col0&~1) ^ sw)] = v0 | (p0v<<16);
                    *(u32*)&sT[(grow<<7) + ((col1&~1) ^ sw)] = v1 | (p1v<<16);
                }
            }
        }
        __syncthreads();                                        // S3

        // ======== phase 4: logits = u@Wg2; softmax per point; y -> yB ====
        {
            f32x16 lg0 = {0}, lg1 = {0};
            __builtin_amdgcn_s_setprio(1);
            #pragma unroll
            for (int kk = 0; kk < 8; ++kk) {
                const int kc = (kk<<4) + (hi<<3);
                const f16x8 a  = *(const f16x8*)&sT[(arow<<7) + (kc ^ asw)];
                const f16x8 w0 = *(const f16x8*)&WTg2[(size_t)col0*C + kc];
                const f16x8 w1 = *(const f16x8*)&WTg2[(size_t)col1*C + kc];
                lg0 = mfma32(a, w0, lg0);
                lg1 = mfma32(a, w1, lg1);
            }
            __builtin_amdgcn_s_setprio(0);

            // 4 (ct, pt) combos; regs r<8 -> pt0, r>=8 -> pt1
#define SOFTMAX_Y(LG, POS, ALV, RB, PT, COLX)                                 \
            {                                                                 \
                float mx = -1e30f;                                            \
                _Pragma("unroll")                                             \
                for (int r = 0; r < 8; ++r) mx = fmaxf(mx, LG[RB + r]);       \
                mx = fmaxf(mx, __shfl_xor(mx, 32));                           \
                float den = 0.f, yp = 0.f;                                    \
                _Pragma("unroll")                                             \
                for (int r = 0; r < 8; ++r) {                                 \
                    const float e = __expf(LG[RB + r] - mx);                  \
                    den += e;                                                 \
                    yp  = fmaf(e, f16tof(ALV[RB + r]) + POS[RB + r], yp);     \
                }                                                             \
                den += __shfl_xor(den, 32);                                   \
                yp  += __shfl_xor(yp, 32);                                    \
                yp  /= den;                                                   \
                if (hi == 0) yB[(size_t)(PT)*C + (COLX)] = ftof16(yp);        \
            }
            SOFTMAX_Y(lg0, pos0, alv0, 0, pt0, col0)
            SOFTMAX_Y(lg1, pos1, alv1, 0, pt0, col1)
            SOFTMAX_Y(lg0, pos0, alv0, 8, pt1, col0)
            SOFTMAX_Y(lg1, pos1, alv1, 8, pt1, col1)
#undef SOFTMAX_Y
        }
        __syncthreads();                                        // S4
    }
}

// ---------------------------------------------------------------------------
// Kernel 3: out = y @ W_down + b_down + x   (f16 MFMA GEMM, 64 rows/block)
// ---------------------------------------------------------------------------
__global__ __launch_bounds__(512) void k_down(
    const ushort_t* __restrict__ yB,
    const ushort_t* __restrict__ WTdn, const float* __restrict__ bdn,
    const float* __restrict__ x, float* __restrict__ out)
{
    __shared__ ushort_t sY[64*C];
    const int tid = threadIdx.x, lane = tid & 63, wv = tid >> 6;
    const int ncol = (wv<<4) + (lane&15), arow = lane&15;
    const int kgrp = lane>>4, krow0 = kgrp<<3;
    const int r0 = blockIdx.x * 64;

    {
        const int rY = tid>>3, cY = (tid&7)<<4;
        #pragma unroll
        for (int hf = 0; hf < 2; ++hf) {
            const uint4 v = *(const uint4*)&yB[(size_t)(r0+rY)*C + cY + hf*8];
            *(uint4*)&sY[(rY<<7) + ((cY + hf*8) ^ ((rY&7)<<3))] = v;
        }
    }
    __syncthreads();

    f16x8 wf[4]; f32x4 oacc[4];
    #pragma unroll
    for (int kk = 0; kk < 4; ++kk)
        wf[kk] = *(const f16x8*)&WTdn[(size_t)ncol*C + (kk<<5) + krow0];
    #pragma unroll
    for (int m = 0; m < 4; ++m) oacc[m] = (f32x4){0.f,0.f,0.f,0.f};
    __builtin_amdgcn_s_setprio(1);
    #pragma unroll
    for (int m = 0; m < 4; ++m)
        #pragma unroll
        for (int kk = 0; kk < 4; ++kk) {
            const int row = (m<<4) + arow;
            const f16x8 af = *(const f16x8*)&sY[(row<<7) + (((kk<<5)+krow0) ^ ((row&7)<<3))];
            oacc[m] = mfma16(af, wf[kk], oacc[m]);
        }
    __builtin_amdgcn_s_setprio(0);
    const float bc = bdn[ncol];
    #pragma unroll
    for (int m = 0; m < 4; ++m)
        #pragma unroll
        for (int r = 0; r < 4; ++r) {
            const int row = (m<<4) + (kgrp<<2) + r;
            const size_t idx = (size_t)(r0+row)*C + ncol;
            out[idx] = oacc[m][r] + bc + x[idx];
        }
}

// ---------------------------------------------------------------------------
extern "C" void kernel_launch(void* const* d_in, const int* in_sizes, int n_in,
                              void* d_out, int out_size, void* d_ws, size_t ws_size,
                              hipStream_t stream)
{
    const float* x      = (const float*)d_in[0];
    const float* coords = (const float*)d_in[1];
    const int*   nidx   = (const int*)d_in[2];
    const float* W_top  = (const float*)d_in[3];
    const float* b_top  = (const float*)d_in[4];
    const float* W_down = (const float*)d_in[5];
    const float* b_down = (const float*)d_in[6];
    const float* W_phi  = (const float*)d_in[7];
    const float* b_phi  = (const float*)d_in[8];
    const float* W_psi  = (const float*)d_in[9];
    const float* b_psi  = (const float*)d_in[10];
    const float* W_alpha= (const float*)d_in[11];
    const float* b_alpha= (const float*)d_in[12];
    const float* W_d1   = (const float*)d_in[13];
    const float* b_d1   = (const float*)d_in[14];
    const float* W_d2   = (const float*)d_in[15];
    const float* b_d2   = (const float*)d_in[16];
    const float* W_g1   = (const float*)d_in[17];
    const float* b_g1   = (const float*)d_in[18];
    const float* W_g2   = (const float*)d_in[19];
    const float* b_g2   = (const float*)d_in[20];
    (void)b_g2; // softmax shift-invariant

    const int N = in_sizes[0] / C;

    ushort_t* WTt  = (ushort_t*)d_ws;
    ushort_t* WTp  = WTt  + C*C;
    ushort_t* WTs  = WTp  + C*C;
    ushort_t* WTa  = WTs  + C*C;
    ushort_t* WTd2 = WTa  + C*C;
    ushort_t* WTg1 = WTd2 + C*C;
    ushort_t* WTg2 = WTg1 + C*C;
    ushort_t* WTdn = WTg2 + C*C;
    ushort_t* phiB = WTdn + C*C;
    ushort_t* psiB = phiB + (size_t)N*C;
    ushort_t* alfB = psiB + (size_t)N*C;
    ushort_t* yB   = alfB + (size_t)N*C;
    float* out = (float*)d_out;

    hipLaunchKernelGGL(k_prep, dim3(4*C), dim3(C), 0, stream,
        W_top, W_phi, W_psi, W_alpha, WTt, WTp, WTs, WTa);
    hipLaunchKernelGGL(k_prep, dim3(4*C), dim3(C), 0, stream,
        W_d2, W_g1, W_g2, W_down, WTd2, WTg1, WTg2, WTdn);

    hipLaunchKernelGGL(k_qkv2, dim3(N / 64), dim3(512), 0, stream,
        x, WTt, b_top, WTp, b_phi, WTs, b_psi, WTa, b_alpha,
        phiB, psiB, alfB);

    const int ngroups = N / GP;                // 8192
    const int NBLK = 256;
    const int gpb = (ngroups + NBLK - 1) / NBLK;   // 32
    hipLaunchKernelGGL(k_attn13, dim3(NBLK), dim3(512), 0, stream,
        phiB, psiB, alfB, coords, nidx,
        W_d1, b_d1, WTd2, b_d2, WTg1, b_g1, WTg2,
        yB, ngroups, gpb);

    hipLaunchKernelGGL(k_down, dim3(N / 64), dim3(512), 0, stream,
        yB, WTdn, b_down, x, out);
}